// Round 6
// baseline (709.035 us; speedup 1.0000x reference)
//
#include <hip/hip_runtime.h>
#include <stdint.h>

// Viterbi CRF decode: B=1024, T=1024, N=34 (32 tags + START=32 + END=33)
// One wave per batch, 64-thread blocks, grid 1024 = exactly 1 wave/SIMD.
// lane j = target state (j<34 active). Scores held ONE PER LANE (lane j
// owns m_j); the all-to-all broadcast each step is 34x v_readlane into
// SGPRs -- no LDS, no barriers, no lgkmcnt in the forward recursion.
// __launch_bounds__(64, 1): min-waves/EU=1 -> RA budgets the full 512-VGPR
// file. (Rounds 2-5 failure: default 8-wave pressure target -> the 34-reg
// transition row was demoted and RE-LOADED FROM L2 EVERY STEP -- invisible
// in FETCH_SIZE since trans is L2-resident, fatal in latency.)
#define BB 1024
#define TT 1024
#define NN 34
#define NEGV -6969.0f

__device__ __forceinline__ float fmax3(float a, float b, float c) {
    return fmaxf(fmaxf(a, b), c);   // fuses to v_max3_f32
}
__device__ __forceinline__ int imin2(int a, int b) { return a < b ? a : b; }
__device__ __forceinline__ int imin3(int a, int b, int c) {
    return imin2(imin2(a, b), c);   // fuses to v_min3_i32
}
__device__ __forceinline__ float rl(float v, int k) {
    return __int_as_float(__builtin_amdgcn_readlane(__float_as_int(v), k));
}

__global__ __launch_bounds__(64, 1) void viterbi_rl(
        const float* __restrict__ feat,   // [B,T,34]
        const float* __restrict__ trans,  // [34,34]
        unsigned char* __restrict__ bpg,  // workspace [B,T,34] backpointers
        float* __restrict__ out)          // best[B] ++ path[B,T+1]
{
    __shared__ unsigned char Fm[16][NN];  // backtrack level-1 results
    __shared__ int Eb[16];                // backtrack level-2 carries

    const int lane = threadIdx.x & 63;
    const int jm   = (lane < NN) ? lane : (NN - 1);  // clamp idle lanes
    const bool act = (lane < NN);
    const int bg   = blockIdx.x;

    // ---- per-lane constants: transitions row j (34 floats, registers)
    float t[NN];
    {
        const float* trow = trans + jm * NN;
#pragma unroll
        for (int i = 0; i < 8; ++i) {
            float4 v = *reinterpret_cast<const float4*>(trow + 4 * i);
            t[4*i+0] = v.x; t[4*i+1] = v.y; t[4*i+2] = v.z; t[4*i+3] = v.w;
        }
        float2 v2 = *reinterpret_cast<const float2*>(trow + 32);
        t[32] = v2.x; t[33] = v2.y;
    }

    const float* fp = feat + (size_t)bg * TT * NN + jm;
    unsigned char* bpt = bpg + (size_t)bg * TT * NN + lane;

    // 4-deep feature prefetch ring (t = 0..3)
    float fr0 = fp[0*NN], fr1 = fp[1*NN], fr2 = fp[2*NN], fr3 = fp[3*NN];

    // lane j holds score[j]; init: START=0, else NEG (idle lanes never read)
    float mprev = (lane == 32) ? 0.0f : NEGV;

    // one Viterbi step. exact fp order (s+f)+tr; argmax = first index at max.
    // readlane broadcast -> adds -> max3 tree -> eq-tree argmax -> bp store.
    auto vstep = [&](float fv, unsigned char* bpw) {
        float s[NN];                      // uniform -> SGPRs
#pragma unroll
        for (int k = 0; k < NN; ++k) s[k] = rl(mprev, k);
        float w[NN];
#pragma unroll
        for (int k = 0; k < NN; ++k) w[k] = (s[k] + fv) + t[k];
        float a[12];
#pragma unroll
        for (int i = 0; i < 11; ++i) a[i] = fmax3(w[3*i], w[3*i+1], w[3*i+2]);
        a[11] = w[33];
        float b0 = fmax3(a[0], a[1], a[2]), b1 = fmax3(a[3], a[4], a[5]);
        float b2 = fmax3(a[6], a[7], a[8]), b3 = fmax3(a[9], a[10], a[11]);
        float m = fmaxf(fmaxf(b0, b1), fmaxf(b2, b3));
        // argmax: independent eq ops + min3 tree (sentinel 64 = inline const)
        int e[NN];
#pragma unroll
        for (int k = 0; k < NN; ++k) e[k] = (w[k] == m) ? k : 64;
        int r[12];
#pragma unroll
        for (int i = 0; i < 11; ++i) r[i] = imin3(e[3*i], e[3*i+1], e[3*i+2]);
        r[11] = e[33];
        int s0 = imin3(r[0], r[1], r[2]),  s1 = imin3(r[3], r[4], r[5]);
        int s2 = imin3(r[6], r[7], r[8]),  s3 = imin3(r[9], r[10], r[11]);
        int am = imin2(imin2(s0, s1), imin2(s2, s3));
        if (act) *bpw = (unsigned char)am;
        mprev = m;
    };

    // ---- forward: 255 iters x 4 steps (prefetch t+4) + 4-step epilogue
    for (int n = 0; n < 255; ++n) {
        { float f = fr0; fr0 = fp[4*NN]; vstep(f, bpt + 0*NN); }
        { float f = fr1; fr1 = fp[5*NN]; vstep(f, bpt + 1*NN); }
        { float f = fr2; fr2 = fp[6*NN]; vstep(f, bpt + 2*NN); }
        { float f = fr3; fr3 = fp[7*NN]; vstep(f, bpt + 3*NN); }
        fp += 4*NN; bpt += 4*NN;
    }
    vstep(fr0, bpt + 0*NN);
    vstep(fr1, bpt + 1*NN);
    vstep(fr2, bpt + 2*NN);
    vstep(fr3, bpt + 3*NN);
    // lane j's mprev = final score[j] (t=1024)

    // ---- end transition + final argmax (uniform in all lanes via readlane)
    int bi;
    float bm;
    {
        const float* er = trans + (NN - 1) * NN;   // uniform -> s_loads
        float wv[NN];
#pragma unroll
        for (int k = 0; k < NN; ++k) wv[k] = rl(mprev, k) + er[k];
        float a[12];
#pragma unroll
        for (int i = 0; i < 11; ++i) a[i] = fmax3(wv[3*i], wv[3*i+1], wv[3*i+2]);
        a[11] = wv[33];
        float b0 = fmax3(a[0], a[1], a[2]), b1 = fmax3(a[3], a[4], a[5]);
        float b2 = fmax3(a[6], a[7], a[8]), b3 = fmax3(a[9], a[10], a[11]);
        bm = fmaxf(fmaxf(b0, b1), fmaxf(b2, b3));
        int e[NN];
#pragma unroll
        for (int k = 0; k < NN; ++k) e[k] = (wv[k] == bm) ? k : 64;
        int r[12];
#pragma unroll
        for (int i = 0; i < 11; ++i) r[i] = imin3(e[3*i], e[3*i+1], e[3*i+2]);
        r[11] = e[33];
        int s0 = imin3(r[0], r[1], r[2]),  s1 = imin3(r[3], r[4], r[5]);
        int s2 = imin3(r[6], r[7], r[8]),  s3 = imin3(r[9], r[10], r[11]);
        bi = imin2(imin2(s0, s1), imin2(s2, s3));
    }
    if (lane == 0) out[bg] = bm;

    // ---- backtrack on this wave's own bp (stores by this wave; L2-resident)
    asm volatile("s_waitcnt vmcnt(0)" ::: "memory");
    const unsigned char* __restrict__ bb = bpg + (size_t)bg * TT * NN;

    // level-1: 16 chunks x 64 steps x 34 hypotheses; lane (c=lane>>2, sub),
    // 9 interleaved chases per lane (ILP hides L2 latency)
    {
        const int c = lane >> 2;
        const int sub = lane & 3;
        int mv[9];
#pragma unroll
        for (int qi = 0; qi < 9; ++qi) {
            int x = sub + 4 * qi;
            mv[qi] = (x < NN) ? x : (NN - 1);
        }
        const unsigned char* cb = bb + (size_t)c * 64 * NN;
        for (int i = 63; i >= 0; --i) {
            const unsigned char* rb = cb + (size_t)i * NN;
#pragma unroll
            for (int qi = 0; qi < 9; ++qi) mv[qi] = rb[mv[qi]];
        }
#pragma unroll
        for (int qi = 0; qi < 9; ++qi) {
            int x = sub + 4 * qi;
            if (x < NN) Fm[c][x] = (unsigned char)mv[qi];
        }
    }

    // level-2: serial 16-chunk scan (same-wave in-order DS, no barrier)
    if (lane == 0) {
        int e = bi;
        Eb[15] = e;
        for (int c = 15; c >= 1; --c) { e = Fm[c][e]; Eb[c - 1] = e; }
    }

    // emit: winning hypothesis per chunk re-chases and writes the path
    float* po = out + BB + (size_t)bg * (TT + 1);
    if (lane < 16) {
        int c = lane;
        int m = Eb[c];
        for (int i = 63; i >= 0; --i) {
            m = bb[(size_t)((c * 64 + i) * NN) + m];
            po[c * 64 + i] = (float)m;
        }
    }
    if (lane == 16) po[TT] = (float)bi;
}

extern "C" void kernel_launch(void* const* d_in, const int* in_sizes, int n_in,
                              void* d_out, int out_size, void* d_ws, size_t ws_size,
                              hipStream_t stream) {
    const float* feat  = (const float*)d_in[0];   // [1024,1024,34]
    const float* trans = (const float*)d_in[1];   // [34,34]
    float* out = (float*)d_out;                   // 1024 + 1024*1025 floats
    unsigned char* bp = (unsigned char*)d_ws;     // 35,651,584 B backpointers

    viterbi_rl<<<BB, 64, 0, stream>>>(feat, trans, bp, out);
}

// Round 7
// 577.703 us; speedup vs baseline: 1.2273x; 1.2273x over previous
//
#include <hip/hip_runtime.h>
#include <stdint.h>

// Viterbi CRF decode: B=1024, T=1024, N=34 (32 tags + START=32 + END=33)
// Round-0 structure (34j x 4h k-split, LDS ping-pong, lgkm-only barrier)
// with NB=1: one batch per block -> grid 1024 -> 4 blocks/CU (was 2).
// Rounds 1-6 showed the limit is dependency-stall overlap, not the chain:
// 1-wave/SIMD variants all regressed (501-587us, VALUBusy<=57%). More
// independent batch pipelines per CU is the only lever that scales.
#define BB 1024
#define TT 1024
#define NN 34
#define NP 36            // padded state dim in LDS score buffers
#define NB 1             // batches per block (1 -> grid 1024 -> 4 blocks/CU)
#define TPB (NB * 136)   // 136 threads = 34 j x 4 h
#define NEGV -6969.0f
#define PADV -1.0e30f

template<int C>
__device__ __forceinline__ int dpp_i(int x) {
    return __builtin_amdgcn_update_dpp(0, x, C, 0xF, 0xF, true);
}
template<int C>
__device__ __forceinline__ float dpp_f(float x) {
    return __int_as_float(dpp_i<C>(__float_as_int(x)));
}

// Barrier that drains LDS (lgkmcnt) only: global prefetch loads stay in
// flight across steps (plain __syncthreads would force vmcnt(0) -> exposes
// full HBM latency on the critical path every step).
__device__ __forceinline__ void lds_barrier() {
    asm volatile("s_waitcnt lgkmcnt(0)\n\ts_barrier" ::: "memory");
}

__global__ __launch_bounds__(TPB, 3) void viterbi_full(
        const float* __restrict__ feat,   // [B,T,34]
        const float* __restrict__ trans,  // [34,34]
        unsigned char* __restrict__ bpg,  // workspace [B,T,34] backpointers
        float* __restrict__ out)          // best[B] ++ path[B,T+1]
{
    __shared__ float sbuf[2][NB][NP];     // ping-pong score buffers
    __shared__ float fsb[NB][NN];
    __shared__ unsigned char Fm[NB][16][NN];
    __shared__ int Eb[NB][16];
    __shared__ int idxs[NB];

    const int tid = threadIdx.x;
    const int bl  = 0;               // NB=1: single batch slot
    const int r   = tid;
    const int j   = r >> 2;          // 0..33 target state
    const int h   = r & 3;           // k-quarter; quads aligned (136%4==0)
    const int k0  = h * 9;
    const int bg  = blockIdx.x * NB + bl;

    // ---- init LDS score buffers (pads -1e30; init scores: START=0, else NEG)
    for (int e = tid; e < 2 * NB * NP; e += TPB) {
        int kk = e % NP;
        ((float*)sbuf)[e] = (kk >= NN) ? PADV : ((kk == 32) ? 0.0f : NEGV);
    }

    // ---- per-thread constants in registers
    float tr[9];
    int   kreg[9];
#pragma unroll
    for (int i = 0; i < 9; ++i) {
        int k = k0 + i;
        tr[i]   = (k < NN) ? trans[j * NN + k] : 0.0f;
        kreg[i] = k;
    }
    const float trE = (r < NN) ? trans[33 * NN + r] : 0.0f;

    const float* fp = feat + (size_t)bg * TT * NN + j;
    unsigned char* bpt = bpg + (size_t)bg * TT * NN + j;

    // 4-deep feature prefetch ring (t = 0..3)
    float fr0 = fp[0 * NN], fr1 = fp[1 * NN], fr2 = fp[2 * NN], fr3 = fp[3 * NN];

    float* const s0 = &sbuf[0][bl][0];
    float* const s1 = &sbuf[1][bl][0];

    __syncthreads();

    // one Viterbi step: read srd, write swr; exact fp order (s+f)+t;
    // argmax = first index attaining max (tree max + eq-scan + min-index)
    auto vstep = [&](const float* __restrict__ srd, float* __restrict__ swr,
                     float fv, unsigned char* bpw) {
        float vv[9];
#pragma unroll
        for (int i = 0; i < 9; ++i) vv[i] = (srd[k0 + i] + fv) + tr[i];
        float m = fmaxf(fmaxf(fmaxf(vv[0], vv[1]), fmaxf(vv[2], vv[3])),
                        fmaxf(fmaxf(vv[4], vv[5]), fmaxf(vv[6], vv[7])));
        m = fmaxf(m, vv[8]);
        m = fmaxf(m, dpp_f<0xB1>(m));   // quad_perm(1,0,3,2): xor 1
        m = fmaxf(m, dpp_f<0x4E>(m));   // quad_perm(2,3,0,1): xor 2
        int am = 127;
#pragma unroll
        for (int i = 8; i >= 0; --i) am = (vv[i] == m) ? kreg[i] : am;
        int ao = dpp_i<0xB1>(am); am = (ao < am) ? ao : am;
        ao = dpp_i<0x4E>(am);     am = (ao < am) ? ao : am;
        if (h == 0) { swr[j] = m; *bpw = (unsigned char)am; }
        lds_barrier();
    };

    // ---- forward: 255 iters x 4 steps (prefetch t+4) + 4-step epilogue
    for (int n = 0; n < 255; ++n) {
        { float f = fr0; fr0 = fp[4 * NN]; vstep(s0, s1, f, bpt + 0 * NN); }
        { float f = fr1; fr1 = fp[5 * NN]; vstep(s1, s0, f, bpt + 1 * NN); }
        { float f = fr2; fr2 = fp[6 * NN]; vstep(s0, s1, f, bpt + 2 * NN); }
        { float f = fr3; fr3 = fp[7 * NN]; vstep(s1, s0, f, bpt + 3 * NN); }
        fp += 4 * NN; bpt += 4 * NN;
    }
    vstep(s0, s1, fr0, bpt + 0 * NN);
    vstep(s1, s0, fr1, bpt + 1 * NN);
    vstep(s0, s1, fr2, bpt + 2 * NN);
    vstep(s1, s0, fr3, bpt + 3 * NN);
    // final scores (t=1024 even) live in sbuf[0]

    // ---- end transition + final argmax
    if (r < NN) fsb[bl][r] = s0[r] + trE;
    __syncthreads();   // also drains vmcnt: all bp stores of this wave done
    if (r == 0) {
        float bm = fsb[bl][0]; int bi = 0;
        for (int k = 1; k < NN; ++k) {
            float v = fsb[bl][k];
            if (v > bm) { bm = v; bi = k; }
        }
        out[bg] = bm; idxs[bl] = bi;
    }
    __syncthreads();

    // ---- backtrack on this block's own bp (L2-resident, same CU/XCD)
    const unsigned char* __restrict__ bb = bpg + (size_t)bg * TT * NN;

    // level-1: 16 chunks x 64 steps x 34 hypotheses; 136 thr x 4 jobs (ILP)
    {
        int g = (r >= 102) ? 3 : ((r >= 68) ? 2 : ((r >= 34) ? 1 : 0));
        int x = r - 34 * g;
        int c0 = g, c1 = g + 4, c2 = g + 8, c3 = g + 12;
        int m0 = x, m1 = x, m2 = x, m3 = x;
        for (int i = 63; i >= 0; --i) {
            m0 = bb[(size_t)((c0 * 64 + i) * NN) + m0];
            m1 = bb[(size_t)((c1 * 64 + i) * NN) + m1];
            m2 = bb[(size_t)((c2 * 64 + i) * NN) + m2];
            m3 = bb[(size_t)((c3 * 64 + i) * NN) + m3];
        }
        Fm[bl][c0][x] = m0; Fm[bl][c1][x] = m1;
        Fm[bl][c2][x] = m2; Fm[bl][c3][x] = m3;
    }
    __syncthreads();

    // level-2: serial 16-chunk scan
    if (r == 0) {
        int e = idxs[bl];
        Eb[bl][15] = e;
        for (int c = 15; c >= 1; --c) { e = Fm[bl][c][e]; Eb[bl][c - 1] = e; }
    }
    __syncthreads();

    // emit: winning hypothesis per chunk re-chases and writes the path
    float* po = out + BB + (size_t)bg * (TT + 1);
    if (r < 16) {
        int c = r;
        int m = Eb[bl][c];
        for (int i = 63; i >= 0; --i) {
            m = bb[(size_t)((c * 64 + i) * NN) + m];
            po[c * 64 + i] = (float)m;
        }
    }
    if (r == 16) po[TT] = (float)idxs[bl];
}

extern "C" void kernel_launch(void* const* d_in, const int* in_sizes, int n_in,
                              void* d_out, int out_size, void* d_ws, size_t ws_size,
                              hipStream_t stream) {
    const float* feat  = (const float*)d_in[0];   // [1024,1024,34]
    const float* trans = (const float*)d_in[1];   // [34,34]
    float* out = (float*)d_out;                   // 1024 + 1024*1025 floats
    unsigned char* bp = (unsigned char*)d_ws;     // 35,651,584 B backpointers

    viterbi_full<<<BB / NB, TPB, 0, stream>>>(feat, trans, bp, out);
}